// Round 1
// baseline (443.837 us; speedup 1.0000x reference)
//
#include <hip/hip_runtime.h>
#include <math.h>

// FAVOR+ (Performer) non-causal linear attention, b=4 h=8 n=8192 d=64 f=266.
// All GEMMs via mfma_f32_16x16x32_bf16 with hi/lo bf16 split (3 products) ->
// fp32-accurate everywhere. F padded to 288 (18 tiles of 16), padded features
// masked to zero after exp.

typedef __attribute__((ext_vector_type(8))) short s16x8;
typedef __attribute__((ext_vector_type(4))) float f32x4;

#define MFMA16(a,b,c) __builtin_amdgcn_mfma_f32_16x16x32_bf16((a),(b),(c),0,0,0)

__device__ __forceinline__ unsigned short bf16rne(float x){
  unsigned u = __float_as_uint(x);
  u = u + 0x7fffu + ((u >> 16) & 1u);
  return (unsigned short)(u >> 16);
}
__device__ __forceinline__ float bf16tof(unsigned short h){
  return __uint_as_float(((unsigned)h) << 16);
}
__device__ __forceinline__ void cvt_hl8(const float v[8], s16x8& h, s16x8& l){
  #pragma unroll
  for(int j=0;j<8;++j){
    unsigned short hh = bf16rne(v[j]);
    h[j] = (short)hh;
    l[j] = (short)bf16rne(v[j] - bf16tof(hh));
  }
}

// ---------------- prep: scaled/padded proj hi/lo ----------------
__global__ void fa21_prep(const float* __restrict__ proj, short* __restrict__ ph,
                          short* __restrict__ pl, float pscale){
  int idx = blockIdx.x*256 + threadIdx.x;
  if(idx >= 288*64) return;
  int f = idx >> 6, dc = idx & 63;
  float v = (f < 266) ? proj[f*64 + dc]*pscale : 0.f;
  unsigned short hh = bf16rne(v);
  ph[idx] = (short)hh;
  pl[idx] = (short)bf16rne(v - bf16tof(hh));
}

// ---------------- phase 1: kp -> context partials + ksum partials ----------------
// grid 256 = 32 heads x 8 chunks, block 256 (4 waves), 16 iters of 64 rows.
// LDS: proj h/l [288][64] swz, kp h/l f-major [288][64] swz, ksum buf [4][288].
__global__ __launch_bounds__(256,1) void fa21_p1(
    const float* __restrict__ kin, const float* __restrict__ vin,
    const short* __restrict__ pjh, const short* __restrict__ pjl,
    float* __restrict__ ctx_part, float* __restrict__ ksum_part,
    float koff, float diagc){
  extern __shared__ char smem[];
  char* sph = smem;
  char* spl = smem + 36864;
  char* skh = smem + 73728;
  char* skl = smem + 110592;
  float* sks = (float*)(smem + 147456);
  const int tid = threadIdx.x;
  const int w = tid >> 6, lane = tid & 63, g = lane >> 4, q = lane & 15;
  const int bid = blockIdx.x;
  const int head = bid & 31, chunk = bid >> 5;
  for(int i = tid; i < 4*288; i += 256) sks[i] = 0.f;
  for(int i = tid; i < 288*64; i += 256){
    int f = i >> 6, dc = i & 63;
    int byt = (f*128 + dc*2) ^ ((f & 7) << 4);
    *(short*)(sph + byt) = pjh[i];
    *(short*)(spl + byt) = pjl[i];
  }
  __syncthreads();
  const int MtH = w >> 1, fHp = w & 1;   // phi role: 2 M-tiles x 9 f-tiles
  const int fHc = w >> 1, eH  = w & 1;   // ctx role: 9 fM-tiles x 2 e-tiles
  f32x4 acc[9][2];
  #pragma unroll
  for(int a=0;a<9;++a){
    #pragma unroll
    for(int b=0;b<2;++b){ f32x4 z = {0.f,0.f,0.f,0.f}; acc[a][b] = z; }
  }
  float ksacc[9];
  #pragma unroll
  for(int a=0;a<9;++a) ksacc[a] = 0.f;
  const float* kbase = kin + (size_t)head*8192*64;
  const float* vbase = vin + (size_t)head*8192*64;
  #pragma unroll 1
  for(int it = 0; it < 16; ++it){
    const int nb = chunk*1024 + it*64;
    // ---- X A-frags (rows on lanes q, k=d contiguous per lane) + diag
    s16x8 xh[2][2], xl[2][2];
    float diag[2];
    #pragma unroll
    for(int mt=0; mt<2; ++mt){
      const float* rp = kbase + (size_t)(nb + MtH*32 + mt*16 + q)*64;
      float ss = 0.f;
      #pragma unroll
      for(int ks=0; ks<2; ++ks){
        float4 a = *(const float4*)(rp + ks*32 + g*8);
        float4 b = *(const float4*)(rp + ks*32 + g*8 + 4);
        float vv[8] = {a.x,a.y,a.z,a.w,b.x,b.y,b.z,b.w};
        #pragma unroll
        for(int j=0;j<8;++j) ss += vv[j]*vv[j];
        cvt_hl8(vv, xh[mt][ks], xl[mt][ks]);
      }
      ss += __shfl_xor(ss, 16); ss += __shfl_xor(ss, 32);
      diag[mt] = ss * diagc;
    }
    // ---- phi: S = X * projT (3-product split)
    f32x4 S[2][9];
    #pragma unroll
    for(int mt=0;mt<2;++mt){
      #pragma unroll
      for(int ftl=0;ftl<9;++ftl){ f32x4 z = {0.f,0.f,0.f,0.f}; S[mt][ftl] = z; }
    }
    #pragma unroll
    for(int ftl=0; ftl<9; ++ftl){
      const int f = (fHp*9 + ftl)*16 + q;
      s16x8 bph[2], bpl[2];
      #pragma unroll
      for(int ks=0; ks<2; ++ks){
        int byt = (f*128 + ks*64 + g*16) ^ ((f & 7) << 4);
        bph[ks] = *(const s16x8*)(sph + byt);
        bpl[ks] = *(const s16x8*)(spl + byt);
      }
      #pragma unroll
      for(int mt=0; mt<2; ++mt){
        #pragma unroll
        for(int ks=0; ks<2; ++ks){
          S[mt][ftl] = MFMA16(xh[mt][ks], bph[ks], S[mt][ftl]);
          S[mt][ftl] = MFMA16(xl[mt][ks], bph[ks], S[mt][ftl]);
          S[mt][ftl] = MFMA16(xh[mt][ks], bpl[ks], S[mt][ftl]);
        }
      }
    }
    // ---- kp = exp2(S' - diag' + koff), mask f>=266, ksum, write LDS (f-major swz)
    #pragma unroll
    for(int mt=0; mt<2; ++mt){
      float dgv[4];
      #pragma unroll
      for(int i=0;i<4;++i) dgv[i] = __shfl(diag[mt], 4*g + i);
      #pragma unroll
      for(int ftl=0; ftl<9; ++ftl){
        const int f = (fHp*9 + ftl)*16 + q;
        const bool live = (f < 266);
        float p[4];
        #pragma unroll
        for(int i=0;i<4;++i){
          float e = exp2f(S[mt][ftl][i] - dgv[i] + koff);
          p[i] = live ? e : 0.f;
        }
        ksacc[ftl] += p[0]+p[1]+p[2]+p[3];
        unsigned short h0=bf16rne(p[0]),h1=bf16rne(p[1]),h2=bf16rne(p[2]),h3=bf16rne(p[3]);
        uint2 hv, lv;
        hv.x = (unsigned)h0 | ((unsigned)h1 << 16);
        hv.y = (unsigned)h2 | ((unsigned)h3 << 16);
        lv.x = (unsigned)bf16rne(p[0]-bf16tof(h0)) | ((unsigned)bf16rne(p[1]-bf16tof(h1)) << 16);
        lv.y = (unsigned)bf16rne(p[2]-bf16tof(h2)) | ((unsigned)bf16rne(p[3]-bf16tof(h3)) << 16);
        int n0 = MtH*32 + mt*16 + 4*g;
        int byt = (f*128 + n0*2) ^ ((f & 7) << 4);
        *(uint2*)(skh + byt) = hv;
        *(uint2*)(skl + byt) = lv;
      }
    }
    // ---- V B-frags (strided global dwords; tile stays L1/L2 resident)
    s16x8 vh[2][2], vl[2][2];
    #pragma unroll
    for(int et=0; et<2; ++et){
      const int e = (eH*2 + et)*16 + q;
      #pragma unroll
      for(int ks=0; ks<2; ++ks){
        float vv[8];
        #pragma unroll
        for(int i2=0;i2<8;++i2) vv[i2] = vbase[(size_t)(nb + ks*32 + 8*g + i2)*64 + e];
        cvt_hl8(vv, vh[et][ks], vl[et][ks]);
      }
    }
    __syncthreads();   // kp ready
    // ---- context += kpT * V
    #pragma unroll
    for(int fm=0; fm<9; ++fm){
      const int f = (fHc*9 + fm)*16 + q;
      s16x8 kh[2], kl[2];
      #pragma unroll
      for(int ks=0; ks<2; ++ks){
        int byt = (f*128 + ks*64 + g*16) ^ ((f & 7) << 4);
        kh[ks] = *(const s16x8*)(skh + byt);
        kl[ks] = *(const s16x8*)(skl + byt);
      }
      #pragma unroll
      for(int et=0; et<2; ++et){
        #pragma unroll
        for(int ks=0; ks<2; ++ks){
          acc[fm][et] = MFMA16(kh[ks], vh[et][ks], acc[fm][et]);
          acc[fm][et] = MFMA16(kl[ks], vh[et][ks], acc[fm][et]);
          acc[fm][et] = MFMA16(kh[ks], vl[et][ks], acc[fm][et]);
        }
      }
    }
    __syncthreads();   // kp LDS reusable
  }
  // ---- store context partials
  float* cp = ctx_part + (size_t)bid*288*64;
  #pragma unroll
  for(int fm=0; fm<9; ++fm){
    #pragma unroll
    for(int et=0; et<2; ++et){
      #pragma unroll
      for(int i=0;i<4;++i){
        int f = (fHc*9 + fm)*16 + 4*g + i;
        int e = (eH*2 + et)*16 + q;
        cp[f*64 + e] = acc[fm][et][i];
      }
    }
  }
  // ---- ksum partials
  #pragma unroll
  for(int ftl=0; ftl<9; ++ftl){
    float s = ksacc[ftl];
    s += __shfl_xor(s, 16); s += __shfl_xor(s, 32);
    if(g == 0) sks[w*288 + (fHp*9 + ftl)*16 + q] = s;
  }
  __syncthreads();
  for(int i = tid; i < 288; i += 256)
    ksum_part[(size_t)bid*288 + i] = sks[i] + sks[288+i] + sks[576+i] + sks[864+i];
}

// ---------------- reduce: sum 8 chunk partials -> cT hi/lo (e-major) + ksum ----------------
__global__ void fa21_reduce(const float* __restrict__ ctx_part, const float* __restrict__ ksum_part,
                            short* __restrict__ cth, short* __restrict__ ctl, float* __restrict__ ksum){
  int h = blockIdx.x, tid = threadIdx.x;
  for(int idx = tid; idx < 288*64; idx += 256){
    float s = 0.f;
    #pragma unroll
    for(int c=0;c<8;++c) s += ctx_part[(size_t)(h + 32*c)*288*64 + idx];
    int f = idx >> 6, e = idx & 63;
    unsigned short hh = bf16rne(s);
    cth[(size_t)h*64*288 + e*288 + f] = (short)hh;
    ctl[(size_t)h*64*288 + e*288 + f] = (short)bf16rne(s - bf16tof(hh));
  }
  for(int idx = tid; idx < 288; idx += 256){
    float s = 0.f;
    #pragma unroll
    for(int c=0;c<8;++c) s += ksum_part[(size_t)(h + 32*c)*288 + idx];
    ksum[h*288 + idx] = s;
  }
}

// ---------------- phase 2: qp -> out ----------------
// LDS: proj h/l, qp h/l n-major [64][296], rowmax[2][64], denom[2][64].
__global__ __launch_bounds__(256,1) void fa21_p2(
    const float* __restrict__ qin,
    const short* __restrict__ pjh, const short* __restrict__ pjl,
    const short* __restrict__ cth, const short* __restrict__ ctl,
    const float* __restrict__ ksum, float* __restrict__ outp,
    float qoff, float qeps, float diagc){
  extern __shared__ char smem[];
  char* sph = smem;
  char* spl = smem + 36864;
  char* sqh = smem + 73728;
  char* sql = smem + 111616;
  float* rmx = (float*)(smem + 149504);
  float* dnb = (float*)(smem + 150016);
  const int tid = threadIdx.x;
  const int w = tid >> 6, lane = tid & 63, g = lane >> 4, q = lane & 15;
  const int bid = blockIdx.x;
  const int head = bid & 31, chunk = bid >> 5;
  for(int i = tid; i < 288*64; i += 256){
    int f = i >> 6, dc = i & 63;
    int byt = (f*128 + dc*2) ^ ((f & 7) << 4);
    *(short*)(sph + byt) = pjh[i];
    *(short*)(spl + byt) = pjl[i];
  }
  // persistent context B-frags (this wave's e-tile = w), hi/lo
  s16x8 cbh[9], cbl[9];
  const short* cbaseh = cth + (size_t)head*64*288;
  const short* cbasel = ctl + (size_t)head*64*288;
  #pragma unroll
  for(int ks=0; ks<9; ++ks){
    cbh[ks] = *(const s16x8*)(cbaseh + (size_t)(w*16 + q)*288 + ks*32 + 8*g);
    cbl[ks] = *(const s16x8*)(cbasel + (size_t)(w*16 + q)*288 + ks*32 + 8*g);
  }
  const int MtH = w >> 1, fHp = w & 1;
  float ksv[9];
  #pragma unroll
  for(int ftl=0; ftl<9; ++ftl) ksv[ftl] = ksum[head*288 + (fHp*9+ftl)*16 + q];
  const float* qbase = qin + (size_t)head*8192*64;
  float* obase = outp + (size_t)head*8192*64;
  __syncthreads();
  #pragma unroll 1
  for(int it=0; it<16; ++it){
    const int nb = chunk*1024 + it*64;
    s16x8 xh[2][2], xl[2][2];
    float diag[2];
    #pragma unroll
    for(int mt=0; mt<2; ++mt){
      const float* rp = qbase + (size_t)(nb + MtH*32 + mt*16 + q)*64;
      float ss = 0.f;
      #pragma unroll
      for(int ks=0; ks<2; ++ks){
        float4 a = *(const float4*)(rp + ks*32 + g*8);
        float4 b = *(const float4*)(rp + ks*32 + g*8 + 4);
        float vv[8] = {a.x,a.y,a.z,a.w,b.x,b.y,b.z,b.w};
        #pragma unroll
        for(int j=0;j<8;++j) ss += vv[j]*vv[j];
        cvt_hl8(vv, xh[mt][ks], xl[mt][ks]);
      }
      ss += __shfl_xor(ss, 16); ss += __shfl_xor(ss, 32);
      diag[mt] = ss * diagc;
    }
    f32x4 S[2][9];
    #pragma unroll
    for(int mt=0;mt<2;++mt){
      #pragma unroll
      for(int ftl=0;ftl<9;++ftl){ f32x4 z = {0.f,0.f,0.f,0.f}; S[mt][ftl] = z; }
    }
    #pragma unroll
    for(int ftl=0; ftl<9; ++ftl){
      const int f = (fHp*9 + ftl)*16 + q;
      s16x8 bph[2], bpl[2];
      #pragma unroll
      for(int ks=0; ks<2; ++ks){
        int byt = (f*128 + ks*64 + g*16) ^ ((f & 7) << 4);
        bph[ks] = *(const s16x8*)(sph + byt);
        bpl[ks] = *(const s16x8*)(spl + byt);
      }
      #pragma unroll
      for(int mt=0; mt<2; ++mt){
        #pragma unroll
        for(int ks=0; ks<2; ++ks){
          S[mt][ftl] = MFMA16(xh[mt][ks], bph[ks], S[mt][ftl]);
          S[mt][ftl] = MFMA16(xl[mt][ks], bph[ks], S[mt][ftl]);
          S[mt][ftl] = MFMA16(xh[mt][ks], bpl[ks], S[mt][ftl]);
        }
      }
    }
    // rowmax partials (per-wave f-range) -> LDS
    #pragma unroll
    for(int mt=0;mt<2;++mt){
      #pragma unroll
      for(int i=0;i<4;++i){
        float m = -3e38f;
        #pragma unroll
        for(int ftl=0; ftl<9; ++ftl){
          const int f = (fHp*9+ftl)*16 + q;
          float v = (f < 266) ? S[mt][ftl][i] : -3e38f;
          m = fmaxf(m, v);
        }
        m = fmaxf(m, __shfl_xor(m, 1));
        m = fmaxf(m, __shfl_xor(m, 2));
        m = fmaxf(m, __shfl_xor(m, 4));
        m = fmaxf(m, __shfl_xor(m, 8));
        if(q == i) rmx[fHp*64 + MtH*32 + mt*16 + 4*g + i] = m;
      }
    }
    __syncthreads();  // bar1: rowmax partials ready
    float dnp[2][4];
    #pragma unroll
    for(int mt=0;mt<2;++mt){
      #pragma unroll
      for(int i=0;i<4;++i) dnp[mt][i] = 0.f;
    }
    #pragma unroll
    for(int mt=0; mt<2; ++mt){
      float dgv[4], rmv[4];
      #pragma unroll
      for(int i=0;i<4;++i){
        dgv[i] = __shfl(diag[mt], 4*g + i);
        int row = MtH*32 + mt*16 + 4*g + i;
        rmv[i] = fmaxf(rmx[row], rmx[64 + row]);
      }
      #pragma unroll
      for(int ftl=0; ftl<9; ++ftl){
        const int f = (fHp*9 + ftl)*16 + q;
        const bool live = (f < 266);
        #pragma unroll
        for(int i=0;i<4;++i){
          float e = exp2f(S[mt][ftl][i] - dgv[i] - rmv[i] + qoff) + qeps;
          float p = live ? e : 0.f;
          dnp[mt][i] += p * ksv[ftl];
          int n = MtH*32 + mt*16 + 4*g + i;
          unsigned short hh = bf16rne(p);
          *(short*)(sqh + n*592 + f*2) = (short)hh;
          *(short*)(sql + n*592 + f*2) = (short)bf16rne(p - bf16tof(hh));
        }
      }
    }
    #pragma unroll
    for(int mt=0;mt<2;++mt){
      #pragma unroll
      for(int i=0;i<4;++i){
        float s = dnp[mt][i];
        s += __shfl_xor(s, 1); s += __shfl_xor(s, 2);
        s += __shfl_xor(s, 4); s += __shfl_xor(s, 8);
        if(q == i) dnb[fHp*64 + MtH*32 + mt*16 + 4*g + i] = s;
      }
    }
    __syncthreads();  // bar2: qp + denom partials ready
    // out GEMM: this wave's e-tile (= w) x all 64 rows, K=288
    f32x4 oacc[4];
    #pragma unroll
    for(int Mt=0;Mt<4;++Mt){ f32x4 z = {0.f,0.f,0.f,0.f}; oacc[Mt] = z; }
    #pragma unroll
    for(int ks=0; ks<9; ++ks){
      #pragma unroll
      for(int Mt=0; Mt<4; ++Mt){
        int byt = (Mt*16 + q)*592 + ks*64 + g*16;
        s16x8 ah = *(const s16x8*)(sqh + byt);
        s16x8 al = *(const s16x8*)(sql + byt);
        oacc[Mt] = MFMA16(ah, cbh[ks], oacc[Mt]);
        oacc[Mt] = MFMA16(al, cbh[ks], oacc[Mt]);
        oacc[Mt] = MFMA16(ah, cbl[ks], oacc[Mt]);
      }
    }
    #pragma unroll
    for(int Mt=0; Mt<4; ++Mt){
      #pragma unroll
      for(int i=0;i<4;++i){
        int row = Mt*16 + 4*g + i;
        float den = dnb[row] + dnb[64 + row] + 1e-8f;
        float dinv = 1.0f / den;
        obase[(size_t)(nb + row)*64 + w*16 + q] = oacc[Mt][i] * dinv;
      }
    }
    __syncthreads();  // bar3: qp LDS reusable
  }
}

extern "C" void kernel_launch(void* const* d_in, const int* in_sizes, int n_in,
                              void* d_out, int out_size, void* d_ws, size_t ws_size,
                              hipStream_t stream){
  const float* q    = (const float*)d_in[0];
  const float* k    = (const float*)d_in[1];
  const float* v    = (const float*)d_in[2];
  const float* proj = (const float*)d_in[3];
  float* out = (float*)d_out;
  char* ws = (char*)d_ws;
  short* wproj_h = (short*)(ws);
  short* wproj_l = (short*)(ws + 36864);
  float* wctx    = (float*)(ws + 73728);
  float* wksump  = (float*)(ws + 18948096);          // 73728 + 256*73728
  short* wct_h   = (short*)(ws + 19243008);          // + 256*288*4
  short* wct_l   = (short*)(ws + 20422656);          // + 32*64*288*2
  float* wksum   = (float*)(ws + 21602304);          // + 32*64*288*2

  const double LOG2E = 1.4426950408889634;
  const double ln_ratio = -0.5*log(266.0);
  float pscale = (float)(pow(64.0, -0.25) * LOG2E);
  float diagc  = (float)(0.0625 * LOG2E);
  float koff   = (float)((1e-4 + ln_ratio) * LOG2E);
  float qoff   = (float)(ln_ratio * LOG2E);
  float qeps   = (float)(1e-4 / sqrt(266.0));

  hipFuncSetAttribute((const void*)fa21_p1, hipFuncAttributeMaxDynamicSharedMemorySize, 152064);
  hipFuncSetAttribute((const void*)fa21_p2, hipFuncAttributeMaxDynamicSharedMemorySize, 150528);

  fa21_prep<<<72, 256, 0, stream>>>(proj, wproj_h, wproj_l, pscale);
  fa21_p1<<<256, 256, 152064, stream>>>(k, v, wproj_h, wproj_l, wctx, wksump, koff, diagc);
  fa21_reduce<<<32, 256, 0, stream>>>(wctx, wksump, wct_h, wct_l, wksum);
  fa21_p2<<<256, 256, 150528, stream>>>(q, wproj_h, wproj_l, wct_h, wct_l, wksum, out,
                                        qoff, qeps, diagc);
}

// Round 2
// 252.222 us; speedup vs baseline: 1.7597x; 1.7597x over previous
//
#include <hip/hip_runtime.h>
#include <math.h>

// FAVOR+ (Performer) non-causal linear attention, b=4 h=8 n=8192 d=64 f=266.
// Round 2: 8-wave blocks (2 waves/SIMD), wave-local rowmax/denom, kp/qp
// hi-only in LDS, 2-product value GEMMs. phi GEMM stays 3-product hi/lo.

typedef __attribute__((ext_vector_type(8))) short s16x8;
typedef __attribute__((ext_vector_type(4))) float f32x4;

#define MFMA16(a,b,c) __builtin_amdgcn_mfma_f32_16x16x32_bf16((a),(b),(c),0,0,0)

__device__ __forceinline__ unsigned short bf16rne(float x){
  unsigned u = __float_as_uint(x);
  u = u + 0x7fffu + ((u >> 16) & 1u);
  return (unsigned short)(u >> 16);
}
__device__ __forceinline__ float bf16tof(unsigned short h){
  return __uint_as_float(((unsigned)h) << 16);
}
__device__ __forceinline__ void cvt_hl8(const float v[8], s16x8& h, s16x8& l){
  #pragma unroll
  for(int j=0;j<8;++j){
    unsigned short hh = bf16rne(v[j]);
    h[j] = (short)hh;
    l[j] = (short)bf16rne(v[j] - bf16tof(hh));
  }
}
__device__ __forceinline__ void cvt_h8(const float v[8], s16x8& h){
  #pragma unroll
  for(int j=0;j<8;++j) h[j] = (short)bf16rne(v[j]);
}

// ---------------- prep: scaled/padded proj hi/lo ----------------
__global__ void fa21_prep(const float* __restrict__ proj, short* __restrict__ ph,
                          short* __restrict__ pl, float pscale){
  int idx = blockIdx.x*256 + threadIdx.x;
  if(idx >= 288*64) return;
  int f = idx >> 6, dc = idx & 63;
  float v = (f < 266) ? proj[f*64 + dc]*pscale : 0.f;
  unsigned short hh = bf16rne(v);
  ph[idx] = (short)hh;
  pl[idx] = (short)bf16rne(v - bf16tof(hh));
}

// ---------------- phase 1: kp -> context partials + ksum partials ----------------
// grid 256 = 32 heads x 8 chunks, 512 threads (8 waves), 8 iters of 128 rows.
// LDS: proj h/l [288][64] swz(f&7), kp hi f-major [288][128] swz(f&15), sks [8][288].
__global__ __launch_bounds__(512,2) void fa21_p1(
    const float* __restrict__ kin, const float* __restrict__ vin,
    const short* __restrict__ pjh, const short* __restrict__ pjl,
    float* __restrict__ ctx_part, float* __restrict__ ksum_part,
    float koff, float diagc){
  extern __shared__ char smem[];
  char* sph = smem;
  char* spl = smem + 36864;
  char* skh = smem + 73728;
  float* sks = (float*)(smem + 147456);
  const int tid = threadIdx.x;
  const int w = tid >> 6, lane = tid & 63, g = lane >> 4, q = lane & 15;
  const int bid = blockIdx.x;
  const int head = bid & 31, chunk = bid >> 5;
  for(int i = tid; i < 288*64; i += 512){
    int f = i >> 6, dc = i & 63;
    int byt = (f*128 + dc*2) ^ ((f & 7) << 4);
    *(short*)(sph + byt) = pjh[i];
    *(short*)(spl + byt) = pjl[i];
  }
  __syncthreads();
  const int eH = w >> 1, fHc = w & 1;   // ctx role: 2 f-halves x 4 e-tiles
  f32x4 acc[9];
  #pragma unroll
  for(int a=0;a<9;++a){ f32x4 z = {0.f,0.f,0.f,0.f}; acc[a] = z; }
  float ksacc[18];
  #pragma unroll
  for(int a=0;a<18;++a) ksacc[a] = 0.f;
  const float* kbase = kin + (size_t)head*8192*64;
  const float* vbase = vin + (size_t)head*8192*64;
  #pragma unroll 1
  for(int it = 0; it < 8; ++it){
    const int nb = chunk*1024 + it*128;
    // ---- X A-frags: wave rows w*16..+16, lane row = q, k=d contiguous
    s16x8 xh[2], xl[2];
    float diag;
    {
      const float* rp = kbase + (size_t)(nb + w*16 + q)*64;
      float ss = 0.f;
      #pragma unroll
      for(int ks=0; ks<2; ++ks){
        float4 a = *(const float4*)(rp + ks*32 + g*8);
        float4 b = *(const float4*)(rp + ks*32 + g*8 + 4);
        float vv[8] = {a.x,a.y,a.z,a.w,b.x,b.y,b.z,b.w};
        #pragma unroll
        for(int j=0;j<8;++j) ss += vv[j]*vv[j];
        cvt_hl8(vv, xh[ks], xl[ks]);
      }
      ss += __shfl_xor(ss, 16); ss += __shfl_xor(ss, 32);
      diag = ss * diagc;
    }
    float dro[4];
    #pragma unroll
    for(int i=0;i<4;++i) dro[i] = __shfl(diag, 4*g + i) - koff;
    // ---- phi: S = X * projT (3-product), all 18 f-tiles
    f32x4 S[18];
    #pragma unroll
    for(int ftl=0;ftl<18;++ftl){ f32x4 z = {0.f,0.f,0.f,0.f}; S[ftl] = z; }
    #pragma unroll
    for(int ftl=0; ftl<18; ++ftl){
      const int f = ftl*16 + q;
      #pragma unroll
      for(int ks=0; ks<2; ++ks){
        int byt = (f*128 + ks*64 + g*16) ^ ((f & 7) << 4);
        s16x8 bph = *(const s16x8*)(sph + byt);
        s16x8 bpl = *(const s16x8*)(spl + byt);
        S[ftl] = MFMA16(xh[ks], bph, S[ftl]);
        S[ftl] = MFMA16(xl[ks], bph, S[ftl]);
        S[ftl] = MFMA16(xh[ks], bpl, S[ftl]);
      }
    }
    // ---- kp = exp2(S - diag + koff), mask, ksum, pack hi -> LDS f-major swz
    #pragma unroll
    for(int ftl=0; ftl<18; ++ftl){
      const int f = ftl*16 + q;
      const bool live = (f < 266);
      float p[4];
      #pragma unroll
      for(int i=0;i<4;++i){
        float e = exp2f(S[ftl][i] - dro[i]);
        p[i] = live ? e : 0.f;
      }
      ksacc[ftl] += p[0]+p[1]+p[2]+p[3];
      uint2 hv;
      hv.x = (unsigned)bf16rne(p[0]) | ((unsigned)bf16rne(p[1]) << 16);
      hv.y = (unsigned)bf16rne(p[2]) | ((unsigned)bf16rne(p[3]) << 16);
      int byt = (f*256 + (w*16 + 4*g)*2) ^ ((f & 15) << 4);
      *(uint2*)(skh + byt) = hv;
    }
    // ---- V B-frags (this wave's e-tile), hi/lo in regs
    s16x8 vh[4], vl[4];
    {
      const int e = eH*16 + q;
      #pragma unroll
      for(int ks=0; ks<4; ++ks){
        float vv[8];
        #pragma unroll
        for(int i2=0;i2<8;++i2) vv[i2] = vbase[(size_t)(nb + ks*32 + 8*g + i2)*64 + e];
        cvt_hl8(vv, vh[ks], vl[ks]);
      }
    }
    __syncthreads();   // kp ready
    // ---- context += kpT * V (2-product: kh*vh + kh*vl)
    #pragma unroll
    for(int fm=0; fm<9; ++fm){
      const int fg = (fHc*9 + fm)*16 + q;
      #pragma unroll
      for(int ks=0; ks<4; ++ks){
        int byt = (fg*256 + ks*64 + 16*g) ^ ((fg & 15) << 4);
        s16x8 kh = *(const s16x8*)(skh + byt);
        acc[fm] = MFMA16(kh, vh[ks], acc[fm]);
        acc[fm] = MFMA16(kh, vl[ks], acc[fm]);
      }
    }
    __syncthreads();   // kp LDS reusable
  }
  // ---- store context partials
  float* cp = ctx_part + (size_t)bid*288*64;
  #pragma unroll
  for(int fm=0; fm<9; ++fm){
    #pragma unroll
    for(int i=0;i<4;++i){
      int f = (fHc*9 + fm)*16 + 4*g + i;
      int e = eH*16 + q;
      cp[f*64 + e] = acc[fm][i];
    }
  }
  // ---- ksum partials: reduce over g, one writer per (w,f)
  #pragma unroll
  for(int ftl=0; ftl<18; ++ftl){
    float s = ksacc[ftl];
    s += __shfl_xor(s, 16); s += __shfl_xor(s, 32);
    if(g == 0) sks[w*288 + ftl*16 + q] = s;
  }
  __syncthreads();
  for(int i = tid; i < 288; i += 512){
    float s = 0.f;
    #pragma unroll
    for(int ww=0; ww<8; ++ww) s += sks[ww*288 + i];
    ksum_part[(size_t)bid*288 + i] = s;
  }
}

// ---------------- reduce: sum 8 chunk partials -> cT hi/lo (e-major) + ksum ----------------
__global__ void fa21_reduce(const float* __restrict__ ctx_part, const float* __restrict__ ksum_part,
                            short* __restrict__ cth, short* __restrict__ ctl, float* __restrict__ ksum){
  int h = blockIdx.x, tid = threadIdx.x;
  for(int idx = tid; idx < 288*64; idx += 256){
    float s = 0.f;
    #pragma unroll
    for(int c=0;c<8;++c) s += ctx_part[(size_t)(h + 32*c)*288*64 + idx];
    int f = idx >> 6, e = idx & 63;
    unsigned short hh = bf16rne(s);
    cth[(size_t)h*64*288 + e*288 + f] = (short)hh;
    ctl[(size_t)h*64*288 + e*288 + f] = (short)bf16rne(s - bf16tof(hh));
  }
  for(int idx = tid; idx < 288; idx += 256){
    float s = 0.f;
    #pragma unroll
    for(int c=0;c<8;++c) s += ksum_part[(size_t)(h + 32*c)*288 + idx];
    ksum[h*288 + idx] = s;
  }
}

// ---------------- phase 2: qp -> out ----------------
// grid 256, 512 threads (8 waves), 8 iters of 128 rows.
// LDS: proj h/l 72K, qp hi n-major [128][296], dnb[128].
__global__ __launch_bounds__(512,2) void fa21_p2(
    const float* __restrict__ qin,
    const short* __restrict__ pjh, const short* __restrict__ pjl,
    const short* __restrict__ cth, const short* __restrict__ ctl,
    const float* __restrict__ ksum, float* __restrict__ outp,
    float qoff, float qeps, float diagc){
  extern __shared__ char smem[];
  char* sph = smem;
  char* spl = smem + 36864;
  char* sqh = smem + 73728;
  float* dnb = (float*)(smem + 149504);
  const int tid = threadIdx.x;
  const int w = tid >> 6, lane = tid & 63, g = lane >> 4, q = lane & 15;
  const int bid = blockIdx.x;
  const int head = bid & 31, chunk = bid >> 5;
  for(int i = tid; i < 288*64; i += 512){
    int f = i >> 6, dc = i & 63;
    int byt = (f*128 + dc*2) ^ ((f & 7) << 4);
    *(short*)(sph + byt) = pjh[i];
    *(short*)(spl + byt) = pjl[i];
  }
  // persistent context B-frags: this wave's e-tile = w&3, hi/lo
  s16x8 cbh[9], cbl[9];
  const short* cbaseh = cth + (size_t)head*64*288;
  const short* cbasel = ctl + (size_t)head*64*288;
  const int erow = (w & 3)*16 + q;
  #pragma unroll
  for(int ks=0; ks<9; ++ks){
    cbh[ks] = *(const s16x8*)(cbaseh + (size_t)erow*288 + ks*32 + 8*g);
    cbl[ks] = *(const s16x8*)(cbasel + (size_t)erow*288 + ks*32 + 8*g);
  }
  float ksv[18];
  #pragma unroll
  for(int ftl=0; ftl<18; ++ftl) ksv[ftl] = ksum[head*288 + ftl*16 + q];
  const float* qbase = qin + (size_t)head*8192*64;
  float* obase = outp + (size_t)head*8192*64;
  const int rh = w >> 2;
  __syncthreads();
  #pragma unroll 1
  for(int it=0; it<8; ++it){
    const int nb = chunk*1024 + it*128;
    // ---- X A-frags: wave rows w*16..+16
    s16x8 xh[2], xl[2];
    float diag;
    {
      const float* rp = qbase + (size_t)(nb + w*16 + q)*64;
      float ss = 0.f;
      #pragma unroll
      for(int ks=0; ks<2; ++ks){
        float4 a = *(const float4*)(rp + ks*32 + g*8);
        float4 b = *(const float4*)(rp + ks*32 + g*8 + 4);
        float vv[8] = {a.x,a.y,a.z,a.w,b.x,b.y,b.z,b.w};
        #pragma unroll
        for(int j=0;j<8;++j) ss += vv[j]*vv[j];
        cvt_hl8(vv, xh[ks], xl[ks]);
      }
      ss += __shfl_xor(ss, 16); ss += __shfl_xor(ss, 32);
      diag = ss * diagc;
    }
    // ---- phi: all 18 f-tiles (3-product)
    f32x4 S[18];
    #pragma unroll
    for(int ftl=0;ftl<18;++ftl){ f32x4 z = {0.f,0.f,0.f,0.f}; S[ftl] = z; }
    #pragma unroll
    for(int ftl=0; ftl<18; ++ftl){
      const int f = ftl*16 + q;
      #pragma unroll
      for(int ks=0; ks<2; ++ks){
        int byt = (f*128 + ks*64 + g*16) ^ ((f & 7) << 4);
        s16x8 bph = *(const s16x8*)(sph + byt);
        s16x8 bpl = *(const s16x8*)(spl + byt);
        S[ftl] = MFMA16(xh[ks], bph, S[ftl]);
        S[ftl] = MFMA16(xl[ks], bph, S[ftl]);
        S[ftl] = MFMA16(xh[ks], bpl, S[ftl]);
      }
    }
    // ---- rowmax (wave-local: in-lane over ftl, then across q lanes)
    float rmv[4];
    #pragma unroll
    for(int i=0;i<4;++i){
      float m = -3e38f;
      #pragma unroll
      for(int ftl=0; ftl<18; ++ftl){
        const int f = ftl*16 + q;
        float v = (f < 266) ? S[ftl][i] : -3e38f;
        m = fmaxf(m, v);
      }
      m = fmaxf(m, __shfl_xor(m, 1));
      m = fmaxf(m, __shfl_xor(m, 2));
      m = fmaxf(m, __shfl_xor(m, 4));
      m = fmaxf(m, __shfl_xor(m, 8));
      rmv[i] = m;
    }
    float dro[4];
    #pragma unroll
    for(int i=0;i<4;++i) dro[i] = __shfl(diag, 4*g + i) + rmv[i] - qoff;
    // ---- qp = exp2(S - dro) + qeps, denom partial, write hi -> LDS n-major
    float dnp[4] = {0.f,0.f,0.f,0.f};
    #pragma unroll
    for(int ftl=0; ftl<18; ++ftl){
      const int f = ftl*16 + q;
      const bool live = (f < 266);
      #pragma unroll
      for(int i=0;i<4;++i){
        float e = exp2f(S[ftl][i] - dro[i]) + qeps;
        float p = live ? e : 0.f;
        dnp[i] += p * ksv[ftl];
        int n = w*16 + 4*g + i;
        *(short*)(sqh + n*592 + f*2) = (short)bf16rne(p);
      }
    }
    #pragma unroll
    for(int i=0;i<4;++i){
      float s = dnp[i];
      s += __shfl_xor(s, 1); s += __shfl_xor(s, 2);
      s += __shfl_xor(s, 4); s += __shfl_xor(s, 8);
      if(q == i) dnb[w*16 + 4*g + i] = s;
    }
    __syncthreads();  // qp + denom ready
    // ---- out GEMM: wave (row-half rh, e-tile w&3), K=288, 2-product
    f32x4 oacc[4];
    #pragma unroll
    for(int Mt=0;Mt<4;++Mt){ f32x4 z = {0.f,0.f,0.f,0.f}; oacc[Mt] = z; }
    #pragma unroll
    for(int ks=0; ks<9; ++ks){
      #pragma unroll
      for(int Mt=0; Mt<4; ++Mt){
        int byt = (rh*64 + Mt*16 + q)*592 + ks*64 + g*16;
        s16x8 ah = *(const s16x8*)(sqh + byt);
        oacc[Mt] = MFMA16(ah, cbh[ks], oacc[Mt]);
        oacc[Mt] = MFMA16(ah, cbl[ks], oacc[Mt]);
      }
    }
    #pragma unroll
    for(int Mt=0; Mt<4; ++Mt){
      #pragma unroll
      for(int i=0;i<4;++i){
        int row = rh*64 + Mt*16 + 4*g + i;
        float dinv = 1.0f / (dnb[row] + 1e-8f);
        obase[(size_t)(nb + row)*64 + (w&3)*16 + q] = oacc[Mt][i] * dinv;
      }
    }
    __syncthreads();  // qp/dnb LDS reusable
  }
}

extern "C" void kernel_launch(void* const* d_in, const int* in_sizes, int n_in,
                              void* d_out, int out_size, void* d_ws, size_t ws_size,
                              hipStream_t stream){
  const float* q    = (const float*)d_in[0];
  const float* k    = (const float*)d_in[1];
  const float* v    = (const float*)d_in[2];
  const float* proj = (const float*)d_in[3];
  float* out = (float*)d_out;
  char* ws = (char*)d_ws;
  short* wproj_h = (short*)(ws);
  short* wproj_l = (short*)(ws + 36864);
  float* wctx    = (float*)(ws + 73728);
  float* wksump  = (float*)(ws + 18948096);          // 73728 + 256*73728
  short* wct_h   = (short*)(ws + 19243008);          // + 256*288*4
  short* wct_l   = (short*)(ws + 20422656);          // + 32*64*288*2
  float* wksum   = (float*)(ws + 21602304);          // + 32*64*288*2

  const double LOG2E = 1.4426950408889634;
  const double ln_ratio = -0.5*log(266.0);
  float pscale = (float)(pow(64.0, -0.25) * LOG2E);
  float diagc  = (float)(0.0625 * LOG2E);
  float koff   = (float)((1e-4 + ln_ratio) * LOG2E);
  float qoff   = (float)(ln_ratio * LOG2E);
  float qeps   = (float)(1e-4 / sqrt(266.0));

  hipFuncSetAttribute((const void*)fa21_p1, hipFuncAttributeMaxDynamicSharedMemorySize, 156672);
  hipFuncSetAttribute((const void*)fa21_p2, hipFuncAttributeMaxDynamicSharedMemorySize, 150016);

  fa21_prep<<<72, 256, 0, stream>>>(proj, wproj_h, wproj_l, pscale);
  fa21_p1<<<256, 512, 156672, stream>>>(k, v, wproj_h, wproj_l, wctx, wksump, koff, diagc);
  fa21_reduce<<<32, 256, 0, stream>>>(wctx, wksump, wct_h, wct_l, wksum);
  fa21_p2<<<256, 512, 150016, stream>>>(q, wproj_h, wproj_l, wct_h, wct_l, wksum, out,
                                        qoff, qeps, diagc);
}